// Round 4
// baseline (202.367 us; speedup 1.0000x reference)
//
#include <hip/hip_runtime.h>

#define BATCH   4096
#define IN_DIM  1024
#define OUT_DIM 1024
#define NB      8                 // DEGREE + 1
#define NBK     7                 // basis funcs in the GEMM (d=1..7; d=0 is a bias)
#define KD2     (IN_DIM * NBK)    // 7168
// Workspace K-layout (d-major): k = (d-1)*IN_DIM + i, for BOTH A and Bt.
// The GEMM only needs A and Bt to agree on k, so it is layout-agnostic.

typedef __bf16 bf16x8 __attribute__((ext_vector_type(8)));
typedef float  f32x4  __attribute__((ext_vector_type(4)));
typedef unsigned short us8 __attribute__((ext_vector_type(8)));
typedef unsigned short us4 __attribute__((ext_vector_type(4)));

__device__ __forceinline__ unsigned short f2bf(float f) {
    unsigned int u = __float_as_uint(f);
    u += 0x7fffu + ((u >> 16) & 1u);   // round-to-nearest-even
    return (unsigned short)(u >> 16);
}

// fast tanh: 1 - 2/(e^{2x}+1) via v_exp_f32 + v_rcp_f32; exact limits at +-inf.
__device__ __forceinline__ float fast_tanh(float x) {
    const float LOG2E_X2 = 2.8853900817779268f;   // 2*log2(e)
    float e = __builtin_amdgcn_exp2f(x * LOG2E_X2);
    return 1.0f - 2.0f * __builtin_amdgcn_rcpf(e + 1.0f);
}

__device__ __forceinline__ void ld_lds16(const unsigned short* g, unsigned short* l) {
    __builtin_amdgcn_global_load_lds(
        (const __attribute__((address_space(1))) void*)g,
        (__attribute__((address_space(3))) void*)l, 16, 0, 0);
}

// ---------------------------------------------------------------------------
// Kernel 1a: basis prep — REWRITTEN for memory concurrency + write width.
// 2048 blocks (8/CU). Thread owns 8 contiguous i of one row:
//   row b = bid*2 + (tid>>7), i0 = (tid&127)*8.
// Both float4 loads issued up front; recurrence in registers; 7 us8 stores
// (16 B/lane -> 1 KB per wave-instruction, fully coalesced per d-plane).
// A[b][(d-1)*1024 + i] = bf16(P_d(tanh(x[b,i]))).
// ---------------------------------------------------------------------------
#define BASIS_BLOCKS (BATCH / 2)               // 2048

__global__ __launch_bounds__(256) void basis_kernel(
    const float* __restrict__ x, const float* __restrict__ ap,
    const float* __restrict__ qp, unsigned short* __restrict__ Aw) {
    const int tid = threadIdx.x;
    const float a = ap[0], q = qp[0];
    const int b  = blockIdx.x * 2 + (tid >> 7);
    const int i0 = (tid & 127) * 8;

    const float* xs = x + (size_t)b * IN_DIM + i0;
    float4 v0 = *(const float4*)xs;          // both loads issued before any use
    float4 v1 = *(const float4*)(xs + 4);

    float xe[8] = {v0.x, v0.y, v0.z, v0.w, v1.x, v1.y, v1.z, v1.w};
    float pm2[8], pm1[8];
    us8 ov;
#pragma unroll
    for (int e = 0; e < 8; ++e) {
        xe[e] = fast_tanh(xe[e]);
        pm2[e] = 1.0f;
        pm1[e] = xe[e] - a;
        ov[e] = f2bf(pm1[e]);
    }
    unsigned short* arow = Aw + (size_t)b * KD2 + i0;
    *(us8*)arow = ov;                         // d=1 plane
    float qn = q, qn1 = 1.0f;
#pragma unroll
    for (int n = 2; n < NB; ++n) {
        qn *= q; qn1 *= q;
#pragma unroll
        for (int e = 0; e < 8; ++e) {
            float pn = (xe[e] - (a + qn)) * pm1[e] - a * qn1 * pm2[e];
            pm2[e] = pm1[e]; pm1[e] = pn;
            ov[e] = f2bf(pn);
        }
        *(us8*)(arow + (size_t)(n - 1) * IN_DIM) = ov;   // d=n plane, 16 B
    }
}

// ---------------------------------------------------------------------------
// Kernel 1b: coeffs repack (d-major) + exact fp32 bias partials. UNCHANGED.
// Patch i0..i0+32 x o0..o0+64 per block; 512 blocks.
// ---------------------------------------------------------------------------
#define REPACK_BLOCKS 512
#define TI 32
#define TO 64
#define RSTR 232    // LDS row stride (ushorts) per o: 224 data + 8 pad

__global__ __launch_bounds__(256) void repack_kernel(
    const float* __restrict__ coeffs,
    unsigned short* __restrict__ Bt,
    float* __restrict__ bias_part) {  // [32][OUT_DIM]
    __shared__ __align__(16) unsigned short lt[TO * RSTR + 512];  // 30.0 KB
    const int tid = threadIdx.x;
    const int bid = blockIdx.x;
    const int g  = bid & 31;
    const int i0 = g * TI;
    const int o0 = (bid >> 5) * TO;
    const int o_local = tid & 63;
    float bpart = 0.f;
#pragma unroll
    for (int pass = 0; pass < 8; ++pass) {
        const int i_local = pass * 4 + (tid >> 6);
        const float* src = coeffs +
            ((size_t)(i0 + i_local) * OUT_DIM + (o0 + o_local)) * NB;
        float4 v0 = *(const float4*)src;
        float4 v1 = *(const float4*)(src + 4);
        bpart += v0.x;                       // d = 0 -> exact fp32 bias
        // LDS stage, d-major per o: lt[o][d-1][i_local] (stride 32 per d)
        unsigned short* dst = lt + o_local * RSTR + i_local;
        dst[0]   = f2bf(v0.y); dst[32]  = f2bf(v0.z); dst[64]  = f2bf(v0.w);
        dst[96]  = f2bf(v1.x); dst[128] = f2bf(v1.y); dst[160] = f2bf(v1.z);
        dst[192] = f2bf(v1.w);
    }
    float* sb = (float*)(lt + TO * RSTR);    // 256 floats
    sb[(tid >> 6) * 64 + o_local] = bpart;
    __syncthreads();
    if (tid < 64)
        bias_part[(size_t)g * OUT_DIM + o0 + tid] =
            sb[tid] + sb[64 + tid] + sb[128 + tid] + sb[192 + tid];
    // write phase: thread -> (o = tid>>2, c = tid&3); 7 d-groups of 64B
#pragma unroll
    for (int p = 0; p < 7; ++p) {
        const int o = tid >> 2;
        const int c = tid & 3;
        us8 v = *(const us8*)(lt + o * RSTR + p * 32 + c * 8);
        *(us8*)(Bt + (size_t)(o0 + o) * KD2 + (size_t)p * IN_DIM + i0 + c * 8) = v;
    }
}

// ---------------------------------------------------------------------------
// Kernel 1c: zero C (for the split-K atomics). UNCHANGED.
// ---------------------------------------------------------------------------
#define ZERO_BLOCKS   (BATCH * OUT_DIM / 4096) // 1024

__global__ __launch_bounds__(256) void zero_kernel(float* __restrict__ C) {
    float* dst = C + (size_t)blockIdx.x * 4096 + threadIdx.x * 4;
    const f32x4 zero = {0.f, 0.f, 0.f, 0.f};
#pragma unroll
    for (int j = 0; j < 4; ++j) *(f32x4*)(dst + j * 1024) = zero;
}

// ---------------------------------------------------------------------------
// Kernel 2: GEMM — UNCHANGED (round-0/3 structure, proven 93.5 us here).
// C[M,N] += A[M,KD2] * Bt[N,KD2]^T  (bf16 -> fp32, split-K x4,
// atomicAdd into zeroed C; ch==0 blocks also add the exact d=0 bias).
// BM=BN=128, BK=64, 256 thr (2x2 waves, 64x64 wave tile). Grid 1024 ->
// 4 blocks/CU. XCD mapping: bidx&7 = m mod 8; all 4 K-chunks of a tile
// share an XCD. LDS swizzle: row r stores logical k-chunk s at s ^ (r&7).
// ---------------------------------------------------------------------------
#define BM 128
#define BN 128
#define BK 64
#define KSPLIT 4
#define KCH (KD2 / KSPLIT)   // 1792 -> 28 iters of BK=64

__global__ __launch_bounds__(256, 4) void gemm_kernel(
    const unsigned short* __restrict__ A,    // bf16 bits [BATCH][KD2]
    const unsigned short* __restrict__ Bt,   // bf16 bits [OUT_DIM][KD2]
    const float* __restrict__ bias_part,     // [32][OUT_DIM]
    float* __restrict__ C) {                 // [BATCH][OUT_DIM], pre-zeroed
    __shared__ __align__(16) unsigned short lA[BM * BK];  // 16 KB
    __shared__ __align__(16) unsigned short lB[BN * BK];  // 16 KB

    const int tid  = threadIdx.x;
    const int bidx = blockIdx.x;
    const int m0 = (((bidx >> 3) & 3) * 8 + (bidx & 7)) * BM;  // low3 -> XCD
    const int n0 = ((bidx >> 5) & 7) * BN;
    const int ch = bidx >> 8;
    const size_t kb = (size_t)ch * KCH;

    const int lane  = tid & 63;
    const int wid   = tid >> 6;
    const int wm    = (wid & 1) * 64;
    const int wn    = (wid >> 1) * 64;
    const int row16 = lane & 15;
    const int quad  = lane >> 4;

    // ds_read element offsets for kk=0; kk=1 is ^32 elems (chunk ^4).
    int aOff[4], bOff[4];
#pragma unroll
    for (int mt = 0; mt < 4; ++mt) {
        int r = wm + mt * 16 + row16;
        aOff[mt] = r * BK + ((quad ^ (r & 7)) * 8);
    }
#pragma unroll
    for (int nt = 0; nt < 4; ++nt) {
        int c = wn + nt * 16 + row16;
        bOff[nt] = c * BK + ((quad ^ (c & 7)) * 8);
    }

    // Staging: tile = 1024 x 16B chunks; thread t -> chunks t + 256*j.
    // Phys chunk c: row r = c>>3, slot s = c&7, global k-chunk = s ^ (r&7).
    const int r0 = tid >> 3, s0 = tid & 7;
    const unsigned short* gA0 = A  + (size_t)(m0 + r0) * KD2 + kb + ((s0 ^ (r0 & 7)) * 8);
    const unsigned short* gB0 = Bt + (size_t)(n0 + r0) * KD2 + kb + ((s0 ^ (r0 & 7)) * 8);
    unsigned short* dA = lA + tid * 8;
    unsigned short* dB = lB + tid * 8;

    f32x4 acc[4][4] = {};

    for (int k0 = 0; k0 < KCH; k0 += BK) {
#pragma unroll
        for (int j = 0; j < 4; ++j)
            ld_lds16(gA0 + k0 + (size_t)j * 32 * KD2, dA + j * 2048);
#pragma unroll
        for (int j = 0; j < 4; ++j)
            ld_lds16(gB0 + k0 + (size_t)j * 32 * KD2, dB + j * 2048);
        __syncthreads();

#pragma unroll
        for (int kk = 0; kk < 2; ++kk) {
            const int xo = kk * 32;
            bf16x8 aF[4], bF[4];
#pragma unroll
            for (int mt = 0; mt < 4; ++mt) aF[mt] = *(const bf16x8*)(lA + (aOff[mt] ^ xo));
#pragma unroll
            for (int nt = 0; nt < 4; ++nt) bF[nt] = *(const bf16x8*)(lB + (bOff[nt] ^ xo));
#pragma unroll
            for (int mt = 0; mt < 4; ++mt)
#pragma unroll
                for (int nt = 0; nt < 4; ++nt)
                    acc[mt][nt] = __builtin_amdgcn_mfma_f32_16x16x32_bf16(
                        aF[mt], bF[nt], acc[mt][nt], 0, 0, 0);
        }
        __syncthreads();
    }

    // ch==0 blocks fold in the exact d=0 bias: sbias[col] = sum_g bias_part[g][col]
    if (ch == 0) {
        float* sb = (float*)lA;   // safe: loop ended with __syncthreads
        if (tid < BN) {
            float s = 0.f;
#pragma unroll
            for (int g = 0; g < 32; ++g) s += bias_part[(size_t)g * OUT_DIM + n0 + tid];
            sb[tid] = s;
        }
        __syncthreads();
    }
    const float* sb = (const float*)lA;

    // C/D layout (m89-verified): col = lane&15, row = quad*4 + reg
#pragma unroll
    for (int mt = 0; mt < 4; ++mt) {
        const int rbase = m0 + wm + mt * 16 + quad * 4;
#pragma unroll
        for (int nt = 0; nt < 4; ++nt) {
            const int col = n0 + wn + nt * 16 + row16;
            const float bv = (ch == 0) ? sb[wn + nt * 16 + row16] : 0.f;
#pragma unroll
            for (int r = 0; r < 4; ++r)
                atomicAdd(&C[(size_t)(rbase + r) * OUT_DIM + col], acc[mt][nt][r] + bv);
        }
    }
}

// ---------------------------------------------------------------------------
// Fallback (only if ws too small): fp32, block per batch row, basis in LDS.
// ---------------------------------------------------------------------------
__global__ __launch_bounds__(256) void fallback_kernel(
    const float* __restrict__ x, const float* __restrict__ ap,
    const float* __restrict__ qp, const float* __restrict__ coeffs,
    float* __restrict__ out) {
    __shared__ float sb[IN_DIM][NB];   // 32 KB
    const int b = blockIdx.x;
    const float a = ap[0], q = qp[0];
    for (int i = threadIdx.x; i < IN_DIM; i += 256) {
        float xt = fast_tanh(x[(size_t)b * IN_DIM + i]);
        float p0 = 1.0f, p1 = xt - a;
        sb[i][0] = p0; sb[i][1] = p1;
        float qn = q, qn1 = 1.0f;
#pragma unroll
        for (int n = 2; n < NB; ++n) {
            qn *= q; qn1 *= q;
            float p2 = (xt - (a + qn)) * p1 - a * qn1 * p0;
            sb[i][n] = p2;
            p0 = p1; p1 = p2;
        }
    }
    __syncthreads();
    float acc[4] = {0.f, 0.f, 0.f, 0.f};
    for (int i = 0; i < IN_DIM; ++i) {
        float bb[NB];
#pragma unroll
        for (int d = 0; d < NB; ++d) bb[d] = sb[i][d];
#pragma unroll
        for (int j = 0; j < 4; ++j) {
            int o = threadIdx.x + j * 256;
            const float* cf = coeffs + ((size_t)i * OUT_DIM + o) * NB;
            float s = 0.f;
#pragma unroll
            for (int d = 0; d < NB; ++d) s += bb[d] * cf[d];
            acc[j] += s;
        }
    }
#pragma unroll
    for (int j = 0; j < 4; ++j)
        out[(size_t)b * OUT_DIM + threadIdx.x + j * 256] = acc[j];
}

// ---------------------------------------------------------------------------
extern "C" void kernel_launch(void* const* d_in, const int* in_sizes, int n_in,
                              void* d_out, int out_size, void* d_ws, size_t ws_size,
                              hipStream_t stream) {
    const float* x      = (const float*)d_in[0];
    const float* a      = (const float*)d_in[1];
    const float* q      = (const float*)d_in[2];
    const float* coeffs = (const float*)d_in[3];
    float* out = (float*)d_out;

    const size_t needA = (size_t)BATCH * KD2 * sizeof(unsigned short);   // 56 MB
    const size_t needB = (size_t)OUT_DIM * KD2 * sizeof(unsigned short); // 14 MB
    const size_t needBias = 32 * (size_t)OUT_DIM * sizeof(float);        // 128 KB

    if (ws_size >= needA + needB + needBias) {
        unsigned short* Aw = (unsigned short*)d_ws;
        unsigned short* Bt = Aw + (size_t)BATCH * KD2;
        float* bias_part = (float*)((char*)d_ws + needA + needB);
        basis_kernel<<<BASIS_BLOCKS, 256, 0, stream>>>(x, a, q, Aw);
        repack_kernel<<<REPACK_BLOCKS, 256, 0, stream>>>(coeffs, Bt, bias_part);
        zero_kernel<<<ZERO_BLOCKS, 256, 0, stream>>>(out);
        gemm_kernel<<<(BATCH / BM) * (OUT_DIM / BN) * KSPLIT, 256, 0, stream>>>(
            Aw, Bt, bias_part, out);
    } else {
        fallback_kernel<<<BATCH, 256, 0, stream>>>(x, a, q, coeffs, out);
    }
}

// Round 6
// 180.198 us; speedup vs baseline: 1.1230x; 1.1230x over previous
//
#include <hip/hip_runtime.h>

#define BATCH   4096
#define IN_DIM  1024
#define OUT_DIM 1024
#define NB      8                 // DEGREE + 1
#define NBK     7                 // basis funcs in the GEMM (d=1..7; d=0 is a bias)
#define KD2     (IN_DIM * NBK)    // 7168
// Workspace K-layout (d-major): k = (d-1)*IN_DIM + i, for BOTH A and Bt.
// NOTE (R5 lesson): hipLaunchCooperativeKernel is NOT graph-capturable in this
// harness (container hang x2). Plain kernels only.

typedef __bf16 bf16x8 __attribute__((ext_vector_type(8)));
typedef float  f32x4  __attribute__((ext_vector_type(4)));
typedef unsigned short us8 __attribute__((ext_vector_type(8)));
typedef unsigned short us4 __attribute__((ext_vector_type(4)));

__device__ __forceinline__ unsigned short f2bf(float f) {
    unsigned int u = __float_as_uint(f);
    u += 0x7fffu + ((u >> 16) & 1u);   // round-to-nearest-even
    return (unsigned short)(u >> 16);
}

// fast tanh: 1 - 2/(e^{2x}+1) via v_exp_f32 + v_rcp_f32; exact limits at +-inf.
__device__ __forceinline__ float fast_tanh(float x) {
    const float LOG2E_X2 = 2.8853900817779268f;   // 2*log2(e)
    float e = __builtin_amdgcn_exp2f(x * LOG2E_X2);
    return 1.0f - 2.0f * __builtin_amdgcn_rcpf(e + 1.0f);
}

__device__ __forceinline__ void ld_lds16(const unsigned short* g, unsigned short* l) {
    __builtin_amdgcn_global_load_lds(
        (const __attribute__((address_space(1))) void*)g,
        (__attribute__((address_space(3))) void*)l, 16, 0, 0);
}

// ---------------------------------------------------------------------------
// Kernel 1a: basis prep — UNCHANGED (R4). 2048 blocks (8/CU). Thread owns 8
// contiguous i of one row; float4 loads up front; 7x us8 16B stores/d-plane.
// A[b][(d-1)*1024 + i] = bf16(P_d(tanh(x[b,i]))).
// ---------------------------------------------------------------------------
#define BASIS_BLOCKS (BATCH / 2)               // 2048

__global__ __launch_bounds__(256) void basis_kernel(
    const float* __restrict__ x, const float* __restrict__ ap,
    const float* __restrict__ qp, unsigned short* __restrict__ Aw) {
    const int tid = threadIdx.x;
    const float a = ap[0], q = qp[0];
    const int b  = blockIdx.x * 2 + (tid >> 7);
    const int i0 = (tid & 127) * 8;

    const float* xs = x + (size_t)b * IN_DIM + i0;
    float4 v0 = *(const float4*)xs;          // both loads issued before any use
    float4 v1 = *(const float4*)(xs + 4);

    float xe[8] = {v0.x, v0.y, v0.z, v0.w, v1.x, v1.y, v1.z, v1.w};
    float pm2[8], pm1[8];
    us8 ov;
#pragma unroll
    for (int e = 0; e < 8; ++e) {
        xe[e] = fast_tanh(xe[e]);
        pm2[e] = 1.0f;
        pm1[e] = xe[e] - a;
        ov[e] = f2bf(pm1[e]);
    }
    unsigned short* arow = Aw + (size_t)b * KD2 + i0;
    *(us8*)arow = ov;                         // d=1 plane
    float qn = q, qn1 = 1.0f;
#pragma unroll
    for (int n = 2; n < NB; ++n) {
        qn *= q; qn1 *= q;
#pragma unroll
        for (int e = 0; e < 8; ++e) {
            float pn = (xe[e] - (a + qn)) * pm1[e] - a * qn1 * pm2[e];
            pm2[e] = pm1[e]; pm1[e] = pn;
            ov[e] = f2bf(pn);
        }
        *(us8*)(arow + (size_t)(n - 1) * IN_DIM) = ov;   // d=n plane, 16 B
    }
}

// ---------------------------------------------------------------------------
// Kernel 1b: coeffs repack (d-major) + exact fp32 bias partials. UNCHANGED.
// ---------------------------------------------------------------------------
#define REPACK_BLOCKS 512
#define TI 32
#define TO 64
#define RSTR 232    // LDS row stride (ushorts) per o: 224 data + 8 pad

__global__ __launch_bounds__(256) void repack_kernel(
    const float* __restrict__ coeffs,
    unsigned short* __restrict__ Bt,
    float* __restrict__ bias_part) {  // [32][OUT_DIM]
    __shared__ __align__(16) unsigned short lt[TO * RSTR + 512];  // 30.0 KB
    const int tid = threadIdx.x;
    const int bid = blockIdx.x;
    const int g  = bid & 31;
    const int i0 = g * TI;
    const int o0 = (bid >> 5) * TO;
    const int o_local = tid & 63;
    float bpart = 0.f;
#pragma unroll
    for (int pass = 0; pass < 8; ++pass) {
        const int i_local = pass * 4 + (tid >> 6);
        const float* src = coeffs +
            ((size_t)(i0 + i_local) * OUT_DIM + (o0 + o_local)) * NB;
        float4 v0 = *(const float4*)src;
        float4 v1 = *(const float4*)(src + 4);
        bpart += v0.x;                       // d = 0 -> exact fp32 bias
        unsigned short* dst = lt + o_local * RSTR + i_local;
        dst[0]   = f2bf(v0.y); dst[32]  = f2bf(v0.z); dst[64]  = f2bf(v0.w);
        dst[96]  = f2bf(v1.x); dst[128] = f2bf(v1.y); dst[160] = f2bf(v1.z);
        dst[192] = f2bf(v1.w);
    }
    float* sb = (float*)(lt + TO * RSTR);    // 256 floats
    sb[(tid >> 6) * 64 + o_local] = bpart;
    __syncthreads();
    if (tid < 64)
        bias_part[(size_t)g * OUT_DIM + o0 + tid] =
            sb[tid] + sb[64 + tid] + sb[128 + tid] + sb[192 + tid];
#pragma unroll
    for (int p = 0; p < 7; ++p) {
        const int o = tid >> 2;
        const int c = tid & 3;
        us8 v = *(const us8*)(lt + o * RSTR + p * 32 + c * 8);
        *(us8*)(Bt + (size_t)(o0 + o) * KD2 + (size_t)p * IN_DIM + i0 + c * 8) = v;
    }
}

// ---------------------------------------------------------------------------
// Kernel 1c: zero C — used ONLY by the atomic fallback path.
// ---------------------------------------------------------------------------
#define ZERO_BLOCKS   (BATCH * OUT_DIM / 4096) // 1024

__global__ __launch_bounds__(256) void zero_kernel(float* __restrict__ C) {
    float* dst = C + (size_t)blockIdx.x * 4096 + threadIdx.x * 4;
    const f32x4 zero = {0.f, 0.f, 0.f, 0.f};
#pragma unroll
    for (int j = 0; j < 4; ++j) *(f32x4*)(dst + j * 1024) = zero;
}

// ---------------------------------------------------------------------------
// Shared GEMM geometry (proven 128x128 body).
// ---------------------------------------------------------------------------
#define BM 128
#define BN 128
#define BK 64
#define KSPLIT 4
#define KCH (KD2 / KSPLIT)   // 1792 -> 28 iters of BK=64

// The K-loop body is identical in both gemm variants; only the epilogue
// differs (plain stores to partial planes vs atomicAdd into zeroed C).
// NEW this round: gemm_store — tests the theory that the 16.8M split-K
// atomicAdds are the ~25 us gap between this gemm (~94 us) and the
// m97-structure prediction (~70 us). ch==0 stores acc+bias directly to C;
// ch=1..3 store partials to Cp planes; reduce_kernel sums them.
// ---------------------------------------------------------------------------
#define GEMM_BODY(EPILOGUE)                                                    \
    __shared__ __align__(16) unsigned short lA[BM * BK];  /* 16 KB */          \
    __shared__ __align__(16) unsigned short lB[BN * BK];  /* 16 KB */          \
    const int tid  = threadIdx.x;                                              \
    const int bidx = blockIdx.x;                                               \
    const int m0 = (((bidx >> 3) & 3) * 8 + (bidx & 7)) * BM;                  \
    const int n0 = ((bidx >> 5) & 7) * BN;                                     \
    const int ch = bidx >> 8;                                                  \
    const size_t kb = (size_t)ch * KCH;                                        \
    const int lane  = tid & 63;                                                \
    const int wid   = tid >> 6;                                                \
    const int wm    = (wid & 1) * 64;                                          \
    const int wn    = (wid >> 1) * 64;                                         \
    const int row16 = lane & 15;                                               \
    const int quad  = lane >> 4;                                               \
    int aOff[4], bOff[4];                                                      \
    _Pragma("unroll") for (int mt = 0; mt < 4; ++mt) {                         \
        int r = wm + mt * 16 + row16;                                          \
        aOff[mt] = r * BK + ((quad ^ (r & 7)) * 8);                            \
    }                                                                          \
    _Pragma("unroll") for (int nt = 0; nt < 4; ++nt) {                         \
        int c = wn + nt * 16 + row16;                                          \
        bOff[nt] = c * BK + ((quad ^ (c & 7)) * 8);                            \
    }                                                                          \
    const int r0 = tid >> 3, s0 = tid & 7;                                     \
    const unsigned short* gA0 = A  + (size_t)(m0 + r0) * KD2 + kb              \
                                + ((s0 ^ (r0 & 7)) * 8);                       \
    const unsigned short* gB0 = Bt + (size_t)(n0 + r0) * KD2 + kb              \
                                + ((s0 ^ (r0 & 7)) * 8);                       \
    unsigned short* dA = lA + tid * 8;                                         \
    unsigned short* dB = lB + tid * 8;                                         \
    f32x4 acc[4][4] = {};                                                      \
    for (int k0 = 0; k0 < KCH; k0 += BK) {                                     \
        _Pragma("unroll") for (int j = 0; j < 4; ++j)                          \
            ld_lds16(gA0 + k0 + (size_t)j * 32 * KD2, dA + j * 2048);          \
        _Pragma("unroll") for (int j = 0; j < 4; ++j)                          \
            ld_lds16(gB0 + k0 + (size_t)j * 32 * KD2, dB + j * 2048);          \
        __syncthreads();                                                       \
        _Pragma("unroll") for (int kk = 0; kk < 2; ++kk) {                     \
            const int xo = kk * 32;                                            \
            bf16x8 aF[4], bF[4];                                               \
            _Pragma("unroll") for (int mt = 0; mt < 4; ++mt)                   \
                aF[mt] = *(const bf16x8*)(lA + (aOff[mt] ^ xo));               \
            _Pragma("unroll") for (int nt = 0; nt < 4; ++nt)                   \
                bF[nt] = *(const bf16x8*)(lB + (bOff[nt] ^ xo));               \
            _Pragma("unroll") for (int mt = 0; mt < 4; ++mt)                   \
                _Pragma("unroll") for (int nt = 0; nt < 4; ++nt)               \
                    acc[mt][nt] = __builtin_amdgcn_mfma_f32_16x16x32_bf16(     \
                        aF[mt], bF[nt], acc[mt][nt], 0, 0, 0);                 \
        }                                                                      \
        __syncthreads();                                                       \
    }                                                                          \
    if (ch == 0) {                                                             \
        float* sbw = (float*)lA;   /* safe: loop ended with __syncthreads */   \
        if (tid < BN) {                                                        \
            float s = 0.f;                                                     \
            _Pragma("unroll") for (int g = 0; g < 32; ++g)                     \
                s += bias_part[(size_t)g * OUT_DIM + n0 + tid];                \
            sbw[tid] = s;                                                      \
        }                                                                      \
        __syncthreads();                                                       \
    }                                                                          \
    const float* sb = (const float*)lA;                                        \
    EPILOGUE

// Plain-store variant: ch==0 -> C (with bias); ch>0 -> Cp plane (ch-1).
__global__ __launch_bounds__(256, 4) void gemm_store(
    const unsigned short* __restrict__ A,    // bf16 bits [BATCH][KD2]
    const unsigned short* __restrict__ Bt,   // bf16 bits [OUT_DIM][KD2]
    const float* __restrict__ bias_part,     // [32][OUT_DIM]
    float* __restrict__ Cp,                  // [3][BATCH*OUT_DIM] partials
    float* __restrict__ C) {                 // [BATCH][OUT_DIM]
    GEMM_BODY(
        float* dst = (ch == 0) ? C : (Cp + (size_t)(ch - 1) * BATCH * OUT_DIM);
        _Pragma("unroll") for (int mt = 0; mt < 4; ++mt) {
            const int rbase = m0 + wm + mt * 16 + quad * 4;
            _Pragma("unroll") for (int nt = 0; nt < 4; ++nt) {
                const int col = n0 + wn + nt * 16 + row16;
                const float bv = (ch == 0) ? sb[wn + nt * 16 + row16] : 0.f;
                _Pragma("unroll") for (int r = 0; r < 4; ++r)
                    dst[(size_t)(rbase + r) * OUT_DIM + col] =
                        acc[mt][nt][r] + bv;
            }
        }
    )
}

// Atomic variant (fallback path, identical to R3/R4 gemm_kernel).
__global__ __launch_bounds__(256, 4) void gemm_atomic(
    const unsigned short* __restrict__ A,
    const unsigned short* __restrict__ Bt,
    const float* __restrict__ bias_part,
    float* __restrict__ C) {                 // pre-zeroed
    GEMM_BODY(
        _Pragma("unroll") for (int mt = 0; mt < 4; ++mt) {
            const int rbase = m0 + wm + mt * 16 + quad * 4;
            _Pragma("unroll") for (int nt = 0; nt < 4; ++nt) {
                const int col = n0 + wn + nt * 16 + row16;
                const float bv = (ch == 0) ? sb[wn + nt * 16 + row16] : 0.f;
                _Pragma("unroll") for (int r = 0; r < 4; ++r)
                    atomicAdd(&C[(size_t)(rbase + r) * OUT_DIM + col],
                              acc[mt][nt][r] + bv);
            }
        }
    )
}

// ---------------------------------------------------------------------------
// Kernel 3: reduce — C += Cp1 + Cp2 + Cp3. 1024 blocks x 256 thr, f32x4,
// fully coalesced. 80 MB traffic ~ 13 us floor.
// ---------------------------------------------------------------------------
__global__ __launch_bounds__(256) void reduce_kernel(
    const float* __restrict__ Cp,   // [3][BATCH*OUT_DIM]
    float* __restrict__ C) {
    const size_t P = (size_t)BATCH * OUT_DIM;
    const size_t base = (size_t)blockIdx.x * 4096 + threadIdx.x * 4;
#pragma unroll
    for (int j = 0; j < 4; ++j) {
        const size_t idx = base + (size_t)j * 1024;
        f32x4 v  = *(const f32x4*)(C + idx);
        f32x4 v1 = *(const f32x4*)(Cp + idx);
        f32x4 v2 = *(const f32x4*)(Cp + P + idx);
        f32x4 v3 = *(const f32x4*)(Cp + 2 * P + idx);
        v = v + v1 + v2 + v3;
        *(f32x4*)(C + idx) = v;
    }
}

// ---------------------------------------------------------------------------
// Fallback (only if ws too small): fp32, block per batch row, basis in LDS.
// ---------------------------------------------------------------------------
__global__ __launch_bounds__(256) void fallback_kernel(
    const float* __restrict__ x, const float* __restrict__ ap,
    const float* __restrict__ qp, const float* __restrict__ coeffs,
    float* __restrict__ out) {
    __shared__ float sb[IN_DIM][NB];   // 32 KB
    const int b = blockIdx.x;
    const float a = ap[0], q = qp[0];
    for (int i = threadIdx.x; i < IN_DIM; i += 256) {
        float xt = fast_tanh(x[(size_t)b * IN_DIM + i]);
        float p0 = 1.0f, p1 = xt - a;
        sb[i][0] = p0; sb[i][1] = p1;
        float qn = q, qn1 = 1.0f;
#pragma unroll
        for (int n = 2; n < NB; ++n) {
            qn *= q; qn1 *= q;
            float p2 = (xt - (a + qn)) * p1 - a * qn1 * p0;
            sb[i][n] = p2;
            p0 = p1; p1 = p2;
        }
    }
    __syncthreads();
    float acc[4] = {0.f, 0.f, 0.f, 0.f};
    for (int i = 0; i < IN_DIM; ++i) {
        float bb[NB];
#pragma unroll
        for (int d = 0; d < NB; ++d) bb[d] = sb[i][d];
#pragma unroll
        for (int j = 0; j < 4; ++j) {
            int o = threadIdx.x + j * 256;
            const float* cf = coeffs + ((size_t)i * OUT_DIM + o) * NB;
            float s = 0.f;
#pragma unroll
            for (int d = 0; d < NB; ++d) s += bb[d] * cf[d];
            acc[j] += s;
        }
    }
#pragma unroll
    for (int j = 0; j < 4; ++j)
        out[(size_t)b * OUT_DIM + threadIdx.x + j * 256] = acc[j];
}

// ---------------------------------------------------------------------------
extern "C" void kernel_launch(void* const* d_in, const int* in_sizes, int n_in,
                              void* d_out, int out_size, void* d_ws, size_t ws_size,
                              hipStream_t stream) {
    const float* x      = (const float*)d_in[0];
    const float* a      = (const float*)d_in[1];
    const float* q      = (const float*)d_in[2];
    const float* coeffs = (const float*)d_in[3];
    float* out = (float*)d_out;

    const size_t needA = (size_t)BATCH * KD2 * sizeof(unsigned short);   // 56 MB
    const size_t needB = (size_t)OUT_DIM * KD2 * sizeof(unsigned short); // 14 MB
    const size_t needBias = 32 * (size_t)OUT_DIM * sizeof(float);        // 128 KB
    const size_t needCp = 3 * (size_t)BATCH * OUT_DIM * sizeof(float);   // 48 MB

    if (ws_size >= needA + needB + needBias + needCp) {
        // Preferred path: plain-store split-K + reduce (no atomics, no zero).
        unsigned short* Aw = (unsigned short*)d_ws;
        unsigned short* Bt = Aw + (size_t)BATCH * KD2;
        float* bias_part = (float*)((char*)d_ws + needA + needB);
        float* Cp = (float*)((char*)d_ws + needA + needB + needBias);
        basis_kernel<<<BASIS_BLOCKS, 256, 0, stream>>>(x, a, q, Aw);
        repack_kernel<<<REPACK_BLOCKS, 256, 0, stream>>>(coeffs, Bt, bias_part);
        gemm_store<<<(BATCH / BM) * (OUT_DIM / BN) * KSPLIT, 256, 0, stream>>>(
            Aw, Bt, bias_part, Cp, out);
        reduce_kernel<<<BATCH * OUT_DIM / 4096, 256, 0, stream>>>(Cp, out);
    } else if (ws_size >= needA + needB + needBias) {
        // Atomic path (R4-identical, known-good 202 us).
        unsigned short* Aw = (unsigned short*)d_ws;
        unsigned short* Bt = Aw + (size_t)BATCH * KD2;
        float* bias_part = (float*)((char*)d_ws + needA + needB);
        basis_kernel<<<BASIS_BLOCKS, 256, 0, stream>>>(x, a, q, Aw);
        repack_kernel<<<REPACK_BLOCKS, 256, 0, stream>>>(coeffs, Bt, bias_part);
        zero_kernel<<<ZERO_BLOCKS, 256, 0, stream>>>(out);
        gemm_atomic<<<(BATCH / BM) * (OUT_DIM / BN) * KSPLIT, 256, 0, stream>>>(
            Aw, Bt, bias_part, out);
    } else {
        fallback_kernel<<<BATCH, 256, 0, stream>>>(x, a, q, coeffs, out);
    }
}